// Round 9
// baseline (344.757 us; speedup 1.0000x reference)
//
#include <hip/hip_runtime.h>

typedef unsigned short u16;
typedef __attribute__((ext_vector_type(4))) float f32x4;
typedef __attribute__((ext_vector_type(8))) short s16x8;
typedef __attribute__((ext_vector_type(4))) unsigned short u16x4;
typedef __attribute__((ext_vector_type(2))) unsigned u32x2;

#define MFMA16(a, b, c) __builtin_amdgcn_mfma_f32_16x16x32_bf16((a), (b), (c), 0, 0, 0)

__device__ __forceinline__ u16 f2bf(float f) {
  union { float f; unsigned u; } v; v.f = f;
  unsigned u = v.u;
  u += 0x7fffu + ((u >> 16) & 1u);   // RNE
  return (u16)(u >> 16);
}

__device__ __forceinline__ unsigned cvtpk(float a, float b) {  // lo<-a, hi<-b (RNE)
  unsigned r;
  asm("v_cvt_pk_bf16_f32 %0, %1, %2" : "=v"(r) : "v"(a), "v"(b));
  return r;
}

__device__ __forceinline__ void gl_lds16(const void* g, void* l) {
  __builtin_amdgcn_global_load_lds(
      (const __attribute__((address_space(1))) void*)g,
      (__attribute__((address_space(3))) void*)l, 16, 0, 0);
}

#define BARF()                                  \
  asm volatile("" ::: "memory");                \
  __builtin_amdgcn_s_barrier();                 \
  asm volatile("" ::: "memory")

// ---------------- fused cast fp32 -> bf16 ----------------
__global__ void cast6(const float* __restrict__ x,
                      const float* __restrict__ w0, const float* __restrict__ w1,
                      const float* __restrict__ w2, const float* __restrict__ w3,
                      u16* __restrict__ ws) {
  const int y = blockIdx.y;
  const float* src;
  u16* dst;
  if (y < 2) { src = x + (size_t)y * 4194304; dst = ws + (size_t)y * 4194304; }
  else {
    src = (y == 2) ? w0 : (y == 3) ? w1 : (y == 4) ? w2 : w3;
    dst = ws + 8388608 + (size_t)(y - 2) * 4194304;
  }
  const int i = blockIdx.x * 256 + threadIdx.x;
  f32x4 v = ((const f32x4*)src)[i];
  u16x4 o;
#pragma unroll
  for (int e = 0; e < 4; ++e) o[e] = f2bf(v[e]);
  ((u16x4*)dst)[i] = o;
}

// ---------------- 256x128 1-barrier/K-tile GEMM core ----------------
// 8 waves (4M x 2N), per-wave 64x64; 16 ds_read_b128 / 32 MFMA per K-tile.
// LDS 96 KiB = 2 buf x {A 256x64 (32K) | B 128x64 (16K)}. One barrier per
// K-tile: {vmcnt(0) [stage(t) is one body old]; barrier [cross-wave vis +
// seals buf^1 readers]; stage(t+1 -> buf^1); reads; MFMA}. Src-col XOR
// pre-swizzle keeps LDS dest linear (gl_lds req) and frag reads conflict-free.
// Measured (r8 gemm_v/gemm_out): ~28 us per 256-block round ~= 1230 TF.
template <int SWAP>
__device__ __forceinline__ void gemm1b_n128(const u16* __restrict__ A,
                                            const u16* __restrict__ Bw,
                                            u16* smem, f32x4 (&acc)[4][4],
                                            int m0, int n0, int tid) {
  const int lane = tid & 63, w = tid >> 6;
  const int ln = lane & 15, quad = lane >> 4, ln7 = lane & 7;
  const int wm = (w >> 1) * 64, wn = (w & 1) * 64;
  const int r0 = tid >> 3;
  const int ck = ((tid & 7) ^ (r0 & 7)) << 3;
  const int sw0 = (quad ^ ln7) << 3, sw1 = ((4 + quad) ^ ln7) << 3;

  s16x8 af[4][2], bf[4][2];

  auto STG = [&](int t) {  // A: 4 loads (rows 0..255), B: 2 loads (rows 0..127)
    u16* dst = smem + (t & 1) * 24576;
    const int kc = t << 6;
    const u16* sa = A + (size_t)(m0 + r0) * 2048 + kc + ck;
#pragma unroll
    for (int g = 0; g < 4; ++g)
      gl_lds16(sa + (size_t)(g * 64) * 2048, dst + g * 4096 + tid * 8);
    const u16* sb = Bw + (size_t)(n0 + r0) * 2048 + kc + ck;
#pragma unroll
    for (int g = 0; g < 2; ++g)
      gl_lds16(sb + (size_t)(g * 64) * 2048, dst + 16384 + g * 4096 + tid * 8);
  };
  auto RD = [&](int buf) {  // 16 reads
    const u16* pa = smem + buf * 24576 + wm * 64;
    const u16* pb = smem + buf * 24576 + 16384 + wn * 64;
#pragma unroll
    for (int tt = 0; tt < 4; ++tt) {
      af[tt][0] = *(const s16x8*)&pa[(tt * 16 + ln) * 64 + sw0];
      af[tt][1] = *(const s16x8*)&pa[(tt * 16 + ln) * 64 + sw1];
      bf[tt][0] = *(const s16x8*)&pb[(tt * 16 + ln) * 64 + sw0];
      bf[tt][1] = *(const s16x8*)&pb[(tt * 16 + ln) * 64 + sw1];
    }
  };

  STG(0);
#pragma unroll 1
  for (int t = 0; t < 32; ++t) {
    asm volatile("s_waitcnt vmcnt(0)" ::: "memory");
    BARF();
    if (t < 31) STG(t + 1);
    RD(t & 1);
    __builtin_amdgcn_s_setprio(1);
#pragma unroll
    for (int tm = 0; tm < 4; ++tm)
#pragma unroll
      for (int tn = 0; tn < 4; ++tn)
#pragma unroll
        for (int ks = 0; ks < 2; ++ks)
          acc[tm][tn] = SWAP ? MFMA16(bf[tn][ks], af[tm][ks], acc[tm][tn])
                             : MFMA16(af[tm][ks], bf[tn][ks], acc[tm][tn]);
    __builtin_amdgcn_s_setprio(0);
  }
  asm volatile("s_waitcnt vmcnt(0) lgkmcnt(0)" ::: "memory");
}

// ---------------- fused Q/K/V projection (one dispatch, 3 rounds) ----------
// z=0: Q -> [B,H,S,D] bf16 scaled (1/sqrt(D))*log2(e); z=1: K -> [B,H,S,D];
// z=2: V -> Vt [B,H,D,S] bf16 (transposed epilogue, SWAP=0).
__global__ __launch_bounds__(512, 2) void gemm_qkv1b(
    const u16* __restrict__ A,
    const u16* __restrict__ W0, const u16* __restrict__ W1, const u16* __restrict__ W2,
    const float* __restrict__ b0, const float* __restrict__ b1, const float* __restrict__ b2,
    u16* __restrict__ Qo, u16* __restrict__ Ko, u16* __restrict__ Vo) {
  __shared__ __align__(16) u16 smem[49152];  // 96 KiB
  const int z = blockIdx.z;
  const u16* Bw = (z == 0) ? W0 : (z == 1) ? W1 : W2;
  const float* bias = (z == 0) ? b0 : (z == 1) ? b1 : b2;

  const int tid = threadIdx.x;
  const int lane = tid & 63, w = tid >> 6;
  const int ln = lane & 15, quad = lane >> 4;
  const int m0 = blockIdx.y * 256, n0 = blockIdx.x * 128;
  const int wm = (w >> 1) * 64, wn = (w & 1) * 64;

  f32x4 acc[4][4] = {};
  if (z < 2) {
    gemm1b_n128<1>(A, Bw, smem, acc, m0, n0, tid);
    u16* out = (z == 0) ? Qo : Ko;
    const float scale = (z == 0) ? 0.1275174306003988f : 1.0f;  // Q: 1/sqrt(128)*log2e
#pragma unroll
    for (int tn = 0; tn < 4; ++tn) {
      const int n_base = n0 + wn + tn * 16 + quad * 4;
      const f32x4 bv = *(const f32x4*)&bias[n_base];
      const int h = n_base >> 7, dl = n_base & 127;
#pragma unroll
      for (int tm = 0; tm < 4; ++tm) {
        const int m = m0 + wm + tm * 16 + ln;
        const int b = m >> 11, s = m & 2047;
        u16x4 ov;
#pragma unroll
        for (int r = 0; r < 4; ++r) ov[r] = f2bf((acc[tm][tn][r] + bv[r]) * scale);
        *(u16x4*)&out[(((size_t)(b * 16 + h)) << 18) + ((size_t)s << 7) + dl] = ov;
      }
    }
  } else {
    gemm1b_n128<0>(A, Bw, smem, acc, m0, n0, tid);
    const int b = m0 >> 11;
#pragma unroll
    for (int tn = 0; tn < 4; ++tn) {
      const int n = n0 + wn + tn * 16 + ln;   // global d index
      const float bv = bias[n];
      const int h = n >> 7, dl = n & 127;
#pragma unroll
      for (int tm = 0; tm < 4; ++tm) {
        const int s_base = (m0 & 2047) + wm + tm * 16 + quad * 4;
        u16x4 ov;
#pragma unroll
        for (int r = 0; r < 4; ++r) ov[r] = f2bf(acc[tm][tn][r] + bv);
        *(u16x4*)&Vo[(((size_t)((b * 16 + h) * 128 + dl)) << 11) + s_base] = ov;
      }
    }
  }
}

// ---------------- output projection GEMM (fp32 out) ----------------
__global__ __launch_bounds__(512, 2) void gemm_out(const u16* __restrict__ A,
                                                   const u16* __restrict__ Bw,
                                                   const float* __restrict__ bias,
                                                   float* __restrict__ out) {
  __shared__ __align__(16) u16 smem[49152];  // 96 KiB
  const int tid = threadIdx.x;
  const int lane = tid & 63, w = tid >> 6;
  const int ln = lane & 15, quad = lane >> 4;
  const int m0 = blockIdx.y * 256, n0 = blockIdx.x * 128;
  const int wm = (w >> 1) * 64, wn = (w & 1) * 64;

  f32x4 acc[4][4] = {};
  gemm1b_n128<1>(A, Bw, smem, acc, m0, n0, tid);
#pragma unroll
  for (int tn = 0; tn < 4; ++tn) {
    const int n_base = n0 + wn + tn * 16 + quad * 4;
    const f32x4 bv = *(const f32x4*)&bias[n_base];
#pragma unroll
    for (int tm = 0; tm < 4; ++tm) {
      const int m = m0 + wm + tm * 16 + ln;
      f32x4 ov;
#pragma unroll
      for (int r = 0; r < 4; ++r) ov[r] = acc[tm][tn][r] + bv[r];
      *(f32x4*)&out[(size_t)m * 2048 + n_base] = ov;
    }
  }
}

// ---------------- causal flash attention (S^T, dbuf K/V, 1 barrier/tile) ----
// Q,K: [B,H,S,D] bf16 (Q pre-scaled by (1/sqrt(D))*log2(e)); Vt: [B,H,D,S].
// LDS 80KB: sP[16K] | sK0|sK1 | sV0|sV1. 2 blocks/CU.
__global__ __launch_bounds__(256, 2) void attn_kernel(const u16* __restrict__ Q,
                                                      const u16* __restrict__ Kp,
                                                      const u16* __restrict__ Vt,
                                                      u16* __restrict__ ctx) {
  __shared__ __align__(16) u16 smem[40960];  // 80 KiB
  u16* sP = smem;                            // 128 x 64

  const int flat = blockIdx.x + (blockIdx.y << 4);
  const int bh = flat >> 4;
  const int i = (flat < 256) ? (15 - (flat & 15)) : (flat & 15);  // pair work-balance
  const size_t base = (size_t)bh << 18;

  const int tid = threadIdx.x, lane = tid & 63, w = tid >> 6;
  const int ln = lane & 15, quad = lane >> 4, ln7 = lane & 7;

  // ---- stage Q tile (32KB) into sK0..sK1 region, swizzled ----
#pragma unroll
  for (int c = 0; c < 8; ++c) {
    const int chunk0 = (c * 4 + w) * 64;
    const int chunk = chunk0 + lane;
    const int row = chunk >> 4, cc = chunk & 15;
    gl_lds16(Q + base + (size_t)((i * 128 + row) * 128 + ((cc ^ (row & 15)) << 3)),
             (char*)(smem + 8192) + chunk0 * 16);
  }
  __syncthreads();
  s16x8 qf[2][4];
#pragma unroll
  for (int qt = 0; qt < 2; ++qt)
#pragma unroll
    for (int kc = 0; kc < 4; ++kc)
      qf[qt][kc] = *(const s16x8*)&smem[8192 + (w * 32 + qt * 16 + ln) * 128 +
                                        (((kc * 4 + quad) ^ ln) << 3)];
  __syncthreads();   // all waves done reading Q region

  auto stageK = [&](int j, int buf) {
    u16* dst = smem + 8192 + buf * 8192;
#pragma unroll
    for (int c = 0; c < 4; ++c) {
      const int chunk0 = (c * 4 + w) * 64;
      const int chunk = chunk0 + lane;
      const int row = chunk >> 4, cc = chunk & 15;
      gl_lds16(Kp + base + (size_t)((j * 64 + row) * 128 + ((cc ^ (row & 15)) << 3)),
               (char*)dst + chunk0 * 16);
    }
  };
  auto stageV = [&](int j, int buf) {
    u16* dst = smem + 24576 + buf * 8192;
#pragma unroll
    for (int c = 0; c < 4; ++c) {
      const int chunk0 = (c * 4 + w) * 64;
      const int chunk = chunk0 + lane;
      const int row = chunk >> 3, cc = chunk & 7;
      gl_lds16(Vt + base + (size_t)(row * 2048 + j * 64 + ((cc ^ (row & 7)) << 3)),
               (char*)dst + chunk0 * 16);
    }
  };

  stageK(0, 0);
  stageV(0, 0);
  __syncthreads();   // tile 0 landed (cold-start latency paid once)

  f32x4 o_acc[8][2] = {};
  float lsum[2] = {0.f, 0.f};
  const int jmax = 2 * i + 1;
  const int qg = i * 128 + w * 32 + ln;  // + qt*16 gives lane's global q

  for (int j = 0; j <= jmax; ++j) {
    const int cb = j & 1;
    if (j < jmax) { stageK(j + 1, cb ^ 1); stageV(j + 1, cb ^ 1); }
    const u16* sK = smem + 8192 + cb * 8192;
    const u16* sV = smem + 24576 + cb * 8192;

    // ---- S^T = K . Q^T (64k x 128q): A = K frags, B = Q regs ----
    f32x4 sacc[4][2] = {};
#pragma unroll
    for (int kc = 0; kc < 4; ++kc) {
      s16x8 kf[4];
#pragma unroll
      for (int kt = 0; kt < 4; ++kt)
        kf[kt] = *(const s16x8*)&sK[(kt * 16 + ln) * 128 + (((kc * 4 + quad) ^ ln) << 3)];
#pragma unroll
      for (int kt = 0; kt < 4; ++kt)
#pragma unroll
        for (int qt = 0; qt < 2; ++qt)
          sacc[kt][qt] = MFMA16(kf[kt], qf[qt][kc], sacc[kt][qt]);
    }

    // ---- exp2 + mask + cvt_pk pack P[q][k] (b64 writes, swizzle q&14) ----
    const bool diag = (j >= 2 * i);
#pragma unroll
    for (int kt = 0; kt < 4; ++kt)
#pragma unroll
      for (int qt = 0; qt < 2; ++qt) {
        f32x4 pv;
#pragma unroll
        for (int r = 0; r < 4; ++r) {
          float p = __builtin_amdgcn_exp2f(sacc[kt][qt][r]);
          const int kg = j * 64 + kt * 16 + quad * 4 + r;
          if (diag && kg > qg + qt * 16) p = 0.f;
          lsum[qt] += p;
          pv[r] = p;
        }
        u32x2 pk2;
        pk2[0] = cvtpk(pv[0], pv[1]);
        pk2[1] = cvtpk(pv[2], pv[3]);
        const int qrow = w * 32 + qt * 16 + ln;
        const int c = kt * 4 + quad;
        *(u32x2*)&sP[qrow * 64 + ((c ^ (qrow & 14)) << 2)] = pk2;
      }
    // sP is wave-private: per-wave seal of the 8 ds_writes is sufficient.
    asm volatile("s_waitcnt lgkmcnt(0)" ::: "memory");
    __builtin_amdgcn_sched_barrier(0);

    // ---- O^T += V . P^T : A = V frags (d rows), B = P frags (q rows) ----
#pragma unroll
    for (int kc = 0; kc < 2; ++kc) {
      s16x8 vf[8], pf[2];
#pragma unroll
      for (int qt = 0; qt < 2; ++qt) {
        const int qrow = w * 32 + qt * 16 + ln;
        const int c0 = kc * 8 + quad * 2;
        pf[qt] = *(const s16x8*)&sP[qrow * 64 + ((c0 ^ (qrow & 14)) << 2)];
      }
#pragma unroll
      for (int dt = 0; dt < 8; ++dt)
        vf[dt] = *(const s16x8*)&sV[(dt * 16 + ln) * 64 + (((kc * 4 + quad) ^ ln7) << 3)];
#pragma unroll
      for (int dt = 0; dt < 8; ++dt)
#pragma unroll
        for (int qt = 0; qt < 2; ++qt)
          o_acc[dt][qt] = MFMA16(vf[dt], pf[qt], o_acc[dt][qt]);
    }
    __syncthreads();  // seals buf[cb] reads (WAR for j+2) + drains j+1 stages
  }

  // ---- epilogue: reduce lsum over quads, scale, u16x4 ctx stores ----
  const int b = bh >> 4, h = bh & 15;
  float rinv[2];
#pragma unroll
  for (int qt = 0; qt < 2; ++qt) {
    float s = lsum[qt];
    s += __shfl_xor(s, 16);
    s += __shfl_xor(s, 32);
    rinv[qt] = __builtin_amdgcn_rcpf(s);
  }
#pragma unroll
  for (int dt = 0; dt < 8; ++dt)
#pragma unroll
    for (int qt = 0; qt < 2; ++qt) {
      const int sg = i * 128 + w * 32 + qt * 16 + ln;
      const int d0 = h * 128 + dt * 16 + quad * 4;
      u16x4 ov;
#pragma unroll
      for (int r = 0; r < 4; ++r) ov[r] = f2bf(o_acc[dt][qt][r] * rinv[qt]);
      *(u16x4*)&ctx[((size_t)b << 22) + (size_t)sg * 2048 + d0] = ov;
    }
}

// ---------------- launch ----------------
extern "C" void kernel_launch(void* const* d_in, const int* in_sizes, int n_in,
                              void* d_out, int out_size, void* d_ws, size_t ws_size,
                              hipStream_t stream) {
  const float* x = (const float*)d_in[0];
  const float* Wq = (const float*)d_in[1];
  const float* bq = (const float*)d_in[2];
  const float* Wk = (const float*)d_in[3];
  const float* bk = (const float*)d_in[4];
  const float* Wv = (const float*)d_in[5];
  const float* bv = (const float*)d_in[6];
  const float* Wo = (const float*)d_in[7];
  const float* bo = (const float*)d_in[8];

  u16* ws = (u16*)d_ws;
  u16* xb = ws;
  u16* Wqb = xb + 8388608;
  u16* Wkb = Wqb + 4194304;
  u16* Wvb = Wkb + 4194304;
  u16* Wob = Wvb + 4194304;
  u16* Qb = Wob + 4194304;    // [B,H,S,D] (pre-scaled w/ log2e fold)
  u16* Kb = Qb + 8388608;     // [B,H,S,D]
  u16* Vtb = Kb + 8388608;    // [B,H,D,S]
  u16* ctxb = Vtb + 8388608;  // [B,S,E]

  cast6<<<dim3(4096, 6), 256, 0, stream>>>(x, Wq, Wk, Wv, Wo, ws);

  gemm_qkv1b<<<dim3(16, 16, 3), 512, 0, stream>>>(xb, Wqb, Wkb, Wvb, bq, bk, bv,
                                                  Qb, Kb, Vtb);

  attn_kernel<<<dim3(16, 32), 256, 0, stream>>>(Qb, Kb, Vtb, ctxb);

  gemm_out<<<dim3(16, 16), 512, 0, stream>>>(ctxb, Wob, bo, (float*)d_out);
}

// Round 10
// 333.674 us; speedup vs baseline: 1.0332x; 1.0332x over previous
//
#include <hip/hip_runtime.h>

typedef unsigned short u16;
typedef __attribute__((ext_vector_type(4))) float f32x4;
typedef __attribute__((ext_vector_type(8))) short s16x8;
typedef __attribute__((ext_vector_type(4))) unsigned short u16x4;
typedef __attribute__((ext_vector_type(2))) unsigned u32x2;

#define MFMA16(a, b, c) __builtin_amdgcn_mfma_f32_16x16x32_bf16((a), (b), (c), 0, 0, 0)

__device__ __forceinline__ u16 f2bf(float f) {
  union { float f; unsigned u; } v; v.f = f;
  unsigned u = v.u;
  u += 0x7fffu + ((u >> 16) & 1u);   // RNE
  return (u16)(u >> 16);
}

__device__ __forceinline__ unsigned cvtpk(float a, float b) {  // lo<-a, hi<-b (RNE)
  unsigned r;
  asm("v_cvt_pk_bf16_f32 %0, %1, %2" : "=v"(r) : "v"(a), "v"(b));
  return r;
}

__device__ __forceinline__ void gl_lds16(const void* g, void* l) {
  __builtin_amdgcn_global_load_lds(
      (const __attribute__((address_space(1))) void*)g,
      (__attribute__((address_space(3))) void*)l, 16, 0, 0);
}

#define BARF()                                  \
  asm volatile("" ::: "memory");                \
  __builtin_amdgcn_s_barrier();                 \
  asm volatile("" ::: "memory")

// ---------------- fused cast fp32 -> bf16 ----------------
__global__ void cast6(const float* __restrict__ x,
                      const float* __restrict__ w0, const float* __restrict__ w1,
                      const float* __restrict__ w2, const float* __restrict__ w3,
                      u16* __restrict__ ws) {
  const int y = blockIdx.y;
  const float* src;
  u16* dst;
  if (y < 2) { src = x + (size_t)y * 4194304; dst = ws + (size_t)y * 4194304; }
  else {
    src = (y == 2) ? w0 : (y == 3) ? w1 : (y == 4) ? w2 : w3;
    dst = ws + 8388608 + (size_t)(y - 2) * 4194304;
  }
  const int i = blockIdx.x * 256 + threadIdx.x;
  f32x4 v = ((const f32x4*)src)[i];
  u16x4 o;
#pragma unroll
  for (int e = 0; e < 4; ++e) o[e] = f2bf(v[e]);
  ((u16x4*)dst)[i] = o;
}

// ---------------- 256x256 4-phase QM-first Q/K GEMM (r6-verified, 63 us) ----
// 8 waves (2M x 4N), per-wave 128x64. One barrier per phase; each phase:
// {MFMA quadrant on frags read LAST phase; issue next frag reads; optional
// stage/seal; barrier}. Reads overlap previous phase's MFMA drain.
__global__ __launch_bounds__(512, 2) void gemm_qk256(
    const u16* __restrict__ A,
    const u16* __restrict__ W0, const u16* __restrict__ W1,
    const float* __restrict__ b0, const float* __restrict__ b1,
    u16* __restrict__ Qo, u16* __restrict__ Ko) {
  __shared__ __align__(16) u16 smem[65536];   // 128 KiB
  const int z = blockIdx.z;
  const u16* Bw = z ? W1 : W0;
  const float* bias = z ? b1 : b0;
  u16* out = z ? Ko : Qo;
  const float scale = z ? 1.0f : 0.1275174306003988f;  // (1/sqrt(128))*log2(e)

  const int tid = threadIdx.x;
  const int lane = tid & 63, w = tid >> 6;
  const int ln = lane & 15, quad = lane >> 4, ln7 = lane & 7;
  const int m0 = blockIdx.y * 256, n0 = blockIdx.x * 256;
  const int wm = (w >> 2) << 7, wn = (w & 3) << 6;

  const int ci0 = tid, ci1 = 512 + tid;
  const int r0 = ci0 >> 3, c0k = ((ci0 & 7) ^ (r0 & 7)) << 3;
  const int r1 = ci1 >> 3, c1k = ((ci1 & 7) ^ (r1 & 7)) << 3;
  const int abase = (w >> 2) << 13;                                   // A half
  const int bbase = 16384 + (((w >> 1) & 1) << 13) + ((w & 1) << 12); // B half+qtr
  const int sw0 = (quad ^ ln7) << 3, sw1 = ((4 + quad) ^ ln7) << 3;

  f32x4 acc[8][4] = {};
  s16x8 af[8][2], bf[4][2];

  auto STGA = [&](int t) {
    u16* dst = smem + ((t & 1) << 15);
    const int kc = (t & 31) << 6;
    const u16* s0 = A + (size_t)(m0 + r0) * 2048 + kc + c0k;
    const u16* s1 = A + (size_t)(m0 + r1) * 2048 + kc + c1k;
    gl_lds16(s0, dst + ci0 * 8);
    gl_lds16(s1, dst + ci1 * 8);
    gl_lds16(s0 + (size_t)128 * 2048, dst + 8192 + ci0 * 8);
    gl_lds16(s1 + (size_t)128 * 2048, dst + 8192 + ci1 * 8);
  };
  auto STGB = [&](int t) {
    u16* dst = smem + ((t & 1) << 15) + 16384;
    const int kc = (t & 31) << 6;
    const u16* s0 = Bw + (size_t)(n0 + r0) * 2048 + kc + c0k;
    const u16* s1 = Bw + (size_t)(n0 + r1) * 2048 + kc + c1k;
    gl_lds16(s0, dst + ci0 * 8);
    gl_lds16(s1, dst + ci1 * 8);
    gl_lds16(s0 + (size_t)128 * 2048, dst + 8192 + ci0 * 8);
    gl_lds16(s1 + (size_t)128 * 2048, dst + 8192 + ci1 * 8);
  };
  auto RDA = [&](int buf, int tm0) {  // 4 frags x 2 ks = 8 reads
    const u16* p = smem + (buf << 15) + abase;
#pragma unroll
    for (int u = 0; u < 4; ++u) {
      const int tt = tm0 + u;
      af[tt][0] = *(const s16x8*)&p[(tt * 16 + ln) * 64 + sw0];
      af[tt][1] = *(const s16x8*)&p[(tt * 16 + ln) * 64 + sw1];
    }
  };
  auto RDB = [&](int buf, int tn0) {  // 2 frags x 2 ks = 4 reads
    const u16* p = smem + (buf << 15) + bbase;
#pragma unroll
    for (int u = 0; u < 2; ++u) {
      const int tt = tn0 + u;
      bf[tt][0] = *(const s16x8*)&p[(tt * 16 + ln) * 64 + sw0];
      bf[tt][1] = *(const s16x8*)&p[(tt * 16 + ln) * 64 + sw1];
    }
  };
  auto QM = [&](int tm0, int tn0) {  // 16 MFMA (one C-quadrant)
    __builtin_amdgcn_s_setprio(1);
#pragma unroll
    for (int tm = tm0; tm < tm0 + 4; ++tm)
#pragma unroll
      for (int tn = tn0; tn < tn0 + 2; ++tn)
#pragma unroll
        for (int ks = 0; ks < 2; ++ks)
          acc[tm][tn] = MFMA16(bf[tn][ks], af[tm][ks], acc[tm][tn]);
    __builtin_amdgcn_s_setprio(0);
  };

  // prologue: tile0 + tile1-A staged; vmcnt(4) -> tile0 landed; first reads.
  STGA(0); STGB(0); STGA(1);
  asm volatile("s_waitcnt vmcnt(4)" ::: "memory");
  BARF();
  RDA(0, 0); RDB(0, 0);

#pragma unroll 1
  for (int u = 0; u < 16; ++u) {
    const int t = 2 * u;
    // ===== tile t (buf0) =====
    QM(0, 0);                  // uses af03,bf01 (read last phase)
    RDA(0, 4);
    STGB(t + 1);               // B(t+1) -> buf1
    BARF();
    QM(4, 0);
    RDB(0, 2);
    BARF();
    QM(4, 2);
    asm volatile("s_waitcnt vmcnt(0)" ::: "memory");  // seal buf1 (stale loads)
    BARF();
    QM(0, 2);
    RDA(1, 0); RDB(1, 0);      // first reads of tile t+1 (buf1)
    STGA(t + 2);               // A(t+2) -> buf0
    BARF();
    // ===== tile t+1 (buf1) =====
    QM(0, 0);
    RDA(1, 4);
    STGB(t + 2);               // B(t+2) -> buf0
    BARF();
    QM(4, 0);
    RDB(1, 2);
    BARF();
    QM(4, 2);
    asm volatile("s_waitcnt vmcnt(0)" ::: "memory");  // seal buf0
    BARF();
    QM(0, 2);
    RDA(0, 0); RDB(0, 0);      // reads of tile t+2 (junk on last iter; dead)
    STGA(t + 3);               // wraps to junk on last iter
    BARF();
  }
  asm volatile("s_waitcnt vmcnt(0) lgkmcnt(0)" ::: "memory");  // drain junk

  // epilogue: D rows = n (quad*4+r), cols = m (ln); [B,H,S,D] store
#pragma unroll
  for (int tn = 0; tn < 4; ++tn) {
    const int n_base = n0 + wn + tn * 16 + quad * 4;
    const f32x4 bv = *(const f32x4*)&bias[n_base];
    const int h = n_base >> 7, dl = n_base & 127;
#pragma unroll
    for (int tm = 0; tm < 8; ++tm) {
      const int m = m0 + wm + tm * 16 + ln;
      const int b = m >> 11, s = m & 2047;
      u16x4 ov;
#pragma unroll
      for (int r = 0; r < 4; ++r) ov[r] = f2bf((acc[tm][tn][r] + bv[r]) * scale);
      *(u16x4*)&out[(((size_t)(b * 16 + h)) << 18) + ((size_t)s << 7) + dl] = ov;
    }
  }
}

// ---------------- 256x128 ring-3 QM-first core (gemm_v / gemm_out) ----------
// 8 waves (4M x 2N), per-wave 64x64; 16 ds_read_b128 / 32 MFMA per K-tile.
// LDS 144 KiB = 3 bufs x {A 256x64 (32K) | B 128x64 (16K)}. 2 phases/tile:
//   ph0: {MFMA ks0 (frags read last phase) | read ks1(buf cur) | stage(t+2)
//         -> buf[(t+2)%3] | BAR}
//   ph1: {MFMA ks1 | vmcnt(6): stage(t+1) landed, stage(t+2) in flight |
//         BAR: cross-wave visibility | read ks0 from buf[(t+1)%3]}
// Stage leash = 2 bodies (~3000 cy >> 900 HBM) -> counted vmcnt is cheap.
// WAR: stage(t+2) hits buf[(t-1)%3]; its last reads (ks1 of t-1) were
// lgkm-sealed by QMks1(t-1) before that wave's ph1 barrier.
template <int SWAP>
__device__ __forceinline__ void gemm3r_n128(const u16* __restrict__ A,
                                            const u16* __restrict__ Bw,
                                            u16* smem, f32x4 (&acc)[4][4],
                                            int m0, int n0, int tid) {
  const int lane = tid & 63, w = tid >> 6;
  const int ln = lane & 15, quad = lane >> 4, ln7 = lane & 7;
  const int wm = (w >> 1) * 64, wn = (w & 1) * 64;
  const int r0 = tid >> 3;
  const int ck = ((tid & 7) ^ (r0 & 7)) << 3;
  const int sw0 = (quad ^ ln7) << 3, sw1 = ((4 + quad) ^ ln7) << 3;

  s16x8 af[4][2], bf[4][2];

  auto STG = [&](int t, int buf) {  // 6 loads: A rows 0..255, B rows 0..127
    u16* dst = smem + buf * 24576;
    const int kc = t << 6;
    const u16* sa = A + (size_t)(m0 + r0) * 2048 + kc + ck;
#pragma unroll
    for (int g = 0; g < 4; ++g)
      gl_lds16(sa + (size_t)(g * 64) * 2048, dst + g * 4096 + tid * 8);
    const u16* sb = Bw + (size_t)(n0 + r0) * 2048 + kc + ck;
#pragma unroll
    for (int g = 0; g < 2; ++g)
      gl_lds16(sb + (size_t)(g * 64) * 2048, dst + 16384 + g * 4096 + tid * 8);
  };
  auto RD0 = [&](int buf) {  // 8 reads, ks=0 half
    const u16* pa = smem + buf * 24576 + wm * 64;
    const u16* pb = smem + buf * 24576 + 16384 + wn * 64;
#pragma unroll
    for (int tt = 0; tt < 4; ++tt) {
      af[tt][0] = *(const s16x8*)&pa[(tt * 16 + ln) * 64 + sw0];
      bf[tt][0] = *(const s16x8*)&pb[(tt * 16 + ln) * 64 + sw0];
    }
  };
  auto RD1 = [&](int buf) {  // 8 reads, ks=1 half
    const u16* pa = smem + buf * 24576 + wm * 64;
    const u16* pb = smem + buf * 24576 + 16384 + wn * 64;
#pragma unroll
    for (int tt = 0; tt < 4; ++tt) {
      af[tt][1] = *(const s16x8*)&pa[(tt * 16 + ln) * 64 + sw1];
      bf[tt][1] = *(const s16x8*)&pb[(tt * 16 + ln) * 64 + sw1];
    }
  };
  auto QM0 = [&]() {  // 16 MFMA on ks=0 frags
    __builtin_amdgcn_s_setprio(1);
#pragma unroll
    for (int tm = 0; tm < 4; ++tm)
#pragma unroll
      for (int tn = 0; tn < 4; ++tn)
        acc[tm][tn] = SWAP ? MFMA16(bf[tn][0], af[tm][0], acc[tm][tn])
                           : MFMA16(af[tm][0], bf[tn][0], acc[tm][tn]);
    __builtin_amdgcn_s_setprio(0);
  };
  auto QM1 = [&]() {  // 16 MFMA on ks=1 frags
    __builtin_amdgcn_s_setprio(1);
#pragma unroll
    for (int tm = 0; tm < 4; ++tm)
#pragma unroll
      for (int tn = 0; tn < 4; ++tn)
        acc[tm][tn] = SWAP ? MFMA16(bf[tn][1], af[tm][1], acc[tm][tn])
                           : MFMA16(af[tm][1], bf[tn][1], acc[tm][tn]);
    __builtin_amdgcn_s_setprio(0);
  };

  // prologue: tiles 0,1 staged; vmcnt(6) -> tile0 landed (tile1 in flight)
  STG(0, 0); STG(1, 1);
  asm volatile("s_waitcnt vmcnt(6)" ::: "memory");
  BARF();
  RD0(0);

  int bc = 0;
#pragma unroll 1
  for (int t = 0; t < 32; ++t) {
    const int bn = (bc == 2) ? 0 : bc + 1;
    const int bs = (bn == 2) ? 0 : bn + 1;
    // ph0
    QM0();
    RD1(bc);
    if (t < 30) STG(t + 2, bs);
    BARF();
    // ph1
    QM1();
    if (t < 30) { asm volatile("s_waitcnt vmcnt(6)" ::: "memory"); }
    else        { asm volatile("s_waitcnt vmcnt(0)" ::: "memory"); }
    BARF();
    if (t < 31) RD0(bn);
    bc = bn;
  }
  asm volatile("s_waitcnt vmcnt(0) lgkmcnt(0)" ::: "memory");
}

// ---------------- V projection GEMM (transposed out) ----------------
__global__ __launch_bounds__(512, 2) void gemm_v(const u16* __restrict__ A,
                                                 const u16* __restrict__ Bw,
                                                 const float* __restrict__ bias,
                                                 u16* __restrict__ Vo) {
  __shared__ __align__(16) u16 smem[73728];  // 144 KiB (3-buf ring)
  const int tid = threadIdx.x;
  const int lane = tid & 63, w = tid >> 6;
  const int ln = lane & 15, quad = lane >> 4;
  const int m0 = blockIdx.y * 256, n0 = blockIdx.x * 128;
  const int wm = (w >> 1) * 64, wn = (w & 1) * 64;

  f32x4 acc[4][4] = {};
  gemm3r_n128<0>(A, Bw, smem, acc, m0, n0, tid);
  const int b = m0 >> 11;
#pragma unroll
  for (int tn = 0; tn < 4; ++tn) {
    const int n = n0 + wn + tn * 16 + ln;   // global d index
    const float bv = bias[n];
    const int h = n >> 7, dl = n & 127;
#pragma unroll
    for (int tm = 0; tm < 4; ++tm) {
      const int s_base = (m0 & 2047) + wm + tm * 16 + quad * 4;
      u16x4 ov;
#pragma unroll
      for (int r = 0; r < 4; ++r) ov[r] = f2bf(acc[tm][tn][r] + bv);
      *(u16x4*)&Vo[(((size_t)((b * 16 + h) * 128 + dl)) << 11) + s_base] = ov;
    }
  }
}

// ---------------- output projection GEMM (fp32 out) ----------------
__global__ __launch_bounds__(512, 2) void gemm_out(const u16* __restrict__ A,
                                                   const u16* __restrict__ Bw,
                                                   const float* __restrict__ bias,
                                                   float* __restrict__ out) {
  __shared__ __align__(16) u16 smem[73728];  // 144 KiB (3-buf ring)
  const int tid = threadIdx.x;
  const int lane = tid & 63, w = tid >> 6;
  const int ln = lane & 15, quad = lane >> 4;
  const int m0 = blockIdx.y * 256, n0 = blockIdx.x * 128;
  const int wm = (w >> 1) * 64, wn = (w & 1) * 64;

  f32x4 acc[4][4] = {};
  gemm3r_n128<1>(A, Bw, smem, acc, m0, n0, tid);
#pragma unroll
  for (int tn = 0; tn < 4; ++tn) {
    const int n_base = n0 + wn + tn * 16 + quad * 4;
    const f32x4 bv = *(const f32x4*)&bias[n_base];
#pragma unroll
    for (int tm = 0; tm < 4; ++tm) {
      const int m = m0 + wm + tm * 16 + ln;
      f32x4 ov;
#pragma unroll
      for (int r = 0; r < 4; ++r) ov[r] = acc[tm][tn][r] + bv[r];
      *(f32x4*)&out[(size_t)m * 2048 + n_base] = ov;
    }
  }
}

// ---------------- causal flash attention (S^T, dbuf K/V, 1 barrier/tile) ----
// Q,K: [B,H,S,D] bf16 (Q pre-scaled by (1/sqrt(D))*log2(e)); Vt: [B,H,D,S].
// LDS 80KB: sP[16K] | sK0|sK1 | sV0|sV1. 2 blocks/CU.
__global__ __launch_bounds__(256, 2) void attn_kernel(const u16* __restrict__ Q,
                                                      const u16* __restrict__ Kp,
                                                      const u16* __restrict__ Vt,
                                                      u16* __restrict__ ctx) {
  __shared__ __align__(16) u16 smem[40960];  // 80 KiB
  u16* sP = smem;                            // 128 x 64

  const int flat = blockIdx.x + (blockIdx.y << 4);
  const int bh = flat >> 4;
  const int i = (flat < 256) ? (15 - (flat & 15)) : (flat & 15);  // pair work-balance
  const size_t base = (size_t)bh << 18;

  const int tid = threadIdx.x, lane = tid & 63, w = tid >> 6;
  const int ln = lane & 15, quad = lane >> 4, ln7 = lane & 7;

  // ---- stage Q tile (32KB) into sK0..sK1 region, swizzled ----
#pragma unroll
  for (int c = 0; c < 8; ++c) {
    const int chunk0 = (c * 4 + w) * 64;
    const int chunk = chunk0 + lane;
    const int row = chunk >> 4, cc = chunk & 15;
    gl_lds16(Q + base + (size_t)((i * 128 + row) * 128 + ((cc ^ (row & 15)) << 3)),
             (char*)(smem + 8192) + chunk0 * 16);
  }
  __syncthreads();
  s16x8 qf[2][4];
#pragma unroll
  for (int qt = 0; qt < 2; ++qt)
#pragma unroll
    for (int kc = 0; kc < 4; ++kc)
      qf[qt][kc] = *(const s16x8*)&smem[8192 + (w * 32 + qt * 16 + ln) * 128 +
                                        (((kc * 4 + quad) ^ ln) << 3)];
  __syncthreads();   // all waves done reading Q region

  auto stageK = [&](int j, int buf) {
    u16* dst = smem + 8192 + buf * 8192;
#pragma unroll
    for (int c = 0; c < 4; ++c) {
      const int chunk0 = (c * 4 + w) * 64;
      const int chunk = chunk0 + lane;
      const int row = chunk >> 4, cc = chunk & 15;
      gl_lds16(Kp + base + (size_t)((j * 64 + row) * 128 + ((cc ^ (row & 15)) << 3)),
               (char*)dst + chunk0 * 16);
    }
  };
  auto stageV = [&](int j, int buf) {
    u16* dst = smem + 24576 + buf * 8192;
#pragma unroll
    for (int c = 0; c < 4; ++c) {
      const int chunk0 = (c * 4 + w) * 64;
      const int chunk = chunk0 + lane;
      const int row = chunk >> 3, cc = chunk & 7;
      gl_lds16(Vt + base + (size_t)(row * 2048 + j * 64 + ((cc ^ (row & 7)) << 3)),
               (char*)dst + chunk0 * 16);
    }
  };

  stageK(0, 0);
  stageV(0, 0);
  __syncthreads();   // tile 0 landed (cold-start latency paid once)

  f32x4 o_acc[8][2] = {};
  float lsum[2] = {0.f, 0.f};
  const int jmax = 2 * i + 1;
  const int qg = i * 128 + w * 32 + ln;  // + qt*16 gives lane's global q

  for (int j = 0; j <= jmax; ++j) {
    const int cb = j & 1;
    if (j < jmax) { stageK(j + 1, cb ^ 1); stageV(j + 1, cb ^ 1); }
    const u16* sK = smem + 8192 + cb * 8192;
    const u16* sV = smem + 24576 + cb * 8192;

    // ---- S^T = K . Q^T (64k x 128q): A = K frags, B = Q regs ----
    f32x4 sacc[4][2] = {};
#pragma unroll
    for (int kc = 0; kc < 4; ++kc) {
      s16x8 kf[4];
#pragma unroll
      for (int kt = 0; kt < 4; ++kt)
        kf[kt] = *(const s16x8*)&sK[(kt * 16 + ln) * 128 + (((kc * 4 + quad) ^ ln) << 3)];
#pragma unroll
      for (int kt = 0; kt < 4; ++kt)
#pragma unroll
        for (int qt = 0; qt < 2; ++qt)
          sacc[kt][qt] = MFMA16(kf[kt], qf[qt][kc], sacc[kt][qt]);
    }

    // ---- exp2 + mask + cvt_pk pack P[q][k] (b64 writes, swizzle q&14) ----
    const bool diag = (j >= 2 * i);
#pragma unroll
    for (int kt = 0; kt < 4; ++kt)
#pragma unroll
      for (int qt = 0; qt < 2; ++qt) {
        f32x4 pv;
#pragma unroll
        for (int r = 0; r < 4; ++r) {
          float p = __builtin_amdgcn_exp2f(sacc[kt][qt][r]);
          const int kg = j * 64 + kt * 16 + quad * 4 + r;
          if (diag && kg > qg + qt * 16) p = 0.f;
          lsum[qt] += p;
          pv[r] = p;
        }
        u32x2 pk2;
        pk2[0] = cvtpk(pv[0], pv[1]);
        pk2[1] = cvtpk(pv[2], pv[3]);
        const int qrow = w * 32 + qt * 16 + ln;
        const int c = kt * 4 + quad;
        *(u32x2*)&sP[qrow * 64 + ((c ^ (qrow & 14)) << 2)] = pk2;
      }
    // sP is wave-private: per-wave seal of the 8 ds_writes is sufficient.
    asm volatile("s_waitcnt lgkmcnt(0)" ::: "memory");
    __builtin_amdgcn_sched_barrier(0);

    // ---- O^T += V . P^T : A = V frags (d rows), B = P frags (q rows) ----
#pragma unroll
    for (int kc = 0; kc < 2; ++kc) {
      s16x8 vf[8], pf[2];
#pragma unroll
      for (int qt = 0; qt < 2; ++qt) {
        const int qrow = w * 32 + qt * 16 + ln;
        const int c0 = kc * 8 + quad * 2;
        pf[qt] = *(const s16x8*)&sP[qrow * 64 + ((c0 ^ (qrow & 14)) << 2)];
      }
#pragma unroll
      for (int dt = 0; dt < 8; ++dt)
        vf[dt] = *(const s16x8*)&sV[(dt * 16 + ln) * 64 + (((kc * 4 + quad) ^ ln7) << 3)];
#pragma unroll
      for (int dt = 0; dt < 8; ++dt)
#pragma unroll
        for (int qt = 0; qt < 2; ++qt)
          o_acc[dt][qt] = MFMA16(vf[dt], pf[qt], o_acc[dt][qt]);
    }
    __syncthreads();  // seals buf[cb] reads (WAR for j+2) + drains j+1 stages
  }

  // ---- epilogue: reduce lsum over quads, scale, u16x4 ctx stores ----
  const int b = bh >> 4, h = bh & 15;
  float rinv[2];
#pragma unroll
  for (int qt = 0; qt < 2; ++qt) {
    float s = lsum[qt];
    s += __shfl_xor(s, 16);
    s += __shfl_xor(s, 32);
    rinv[qt] = __builtin_amdgcn_rcpf(s);
  }
#pragma unroll
  for (int dt = 0; dt < 8; ++dt)
#pragma unroll
    for (int qt = 0; qt < 2; ++qt) {
      const int sg = i * 128 + w * 32 + qt * 16 + ln;
      const int d0 = h * 128 + dt * 16 + quad * 4;
      u16x4 ov;
#pragma unroll
      for (int r = 0; r < 4; ++r) ov[r] = f2bf(o_acc[dt][qt][r] * rinv[qt]);
      *(u16x4*)&ctx[((size_t)b << 22) + (size_t)sg * 2048 + d0] = ov;
    }
}

// ---------------- launch ----------------
extern "C" void kernel_launch(void* const* d_in, const int* in_sizes, int n_in,
                              void* d_out, int out_size, void* d_ws, size_t ws_size,
                              hipStream_t stream) {
  const float* x = (const float*)d_in[0];
  const float* Wq = (const float*)d_in[1];
  const float* bq = (const float*)d_in[2];
  const float* Wk = (const float*)d_in[3];
  const float* bk = (const float*)d_in[4];
  const float* Wv = (const float*)d_in[5];
  const float* bv = (const float*)d_in[6];
  const float* Wo = (const float*)d_in[7];
  const float* bo = (const float*)d_in[8];

  u16* ws = (u16*)d_ws;
  u16* xb = ws;
  u16* Wqb = xb + 8388608;
  u16* Wkb = Wqb + 4194304;
  u16* Wvb = Wkb + 4194304;
  u16* Wob = Wvb + 4194304;
  u16* Qb = Wob + 4194304;    // [B,H,S,D] (pre-scaled w/ log2e fold)
  u16* Kb = Qb + 8388608;     // [B,H,S,D]
  u16* Vtb = Kb + 8388608;    // [B,H,D,S]
  u16* ctxb = Vtb + 8388608;  // [B,S,E]

  cast6<<<dim3(4096, 6), 256, 0, stream>>>(x, Wq, Wk, Wv, Wo, ws);

  gemm_qk256<<<dim3(8, 16, 2), 512, 0, stream>>>(xb, Wqb, Wkb, bq, bk, Qb, Kb);
  gemm_v<<<dim3(16, 16), 512, 0, stream>>>(xb, Wvb, bv, Vtb);

  attn_kernel<<<dim3(16, 32), 256, 0, stream>>>(Qb, Kb, Vtb, ctxb);

  gemm_out<<<dim3(16, 16), 512, 0, stream>>>(ctxb, Wob, bo, (float*)d_out);
}